// Round 5
// baseline (212.529 us; speedup 1.0000x reference)
//
#include <hip/hip_runtime.h>

// B=2, S=2048, E=1024, H=16, D=64; rows = B*S = 4096; 3E = 3072.

typedef __attribute__((ext_vector_type(8))) short short8;     // 8 bf16 (A/B frag)
typedef __attribute__((ext_vector_type(4))) short short4b;    // 4 bf16
typedef __attribute__((ext_vector_type(4))) float floatx4;    // 16x16 C/D frag
typedef __attribute__((ext_vector_type(16))) float floatx16;  // 32x32 C/D frag
typedef unsigned short ushort_t;

static __device__ __forceinline__ ushort_t f2bf(float f) {
    unsigned u = __float_as_uint(f);
    u += 0x7fffu + ((u >> 16) & 1u);      // round-to-nearest-even
    return (ushort_t)(u >> 16);
}
static __device__ __forceinline__ float bf2f(ushort_t h) {
    return __uint_as_float(((unsigned)h) << 16);
}
#if __has_builtin(__builtin_amdgcn_cvt_pk_bf16_f32)
typedef __attribute__((ext_vector_type(2))) __bf16 bf16x2_t;
static __device__ __forceinline__ unsigned pack2bf(float a, float b) {
    bf16x2_t r = __builtin_amdgcn_cvt_pk_bf16_f32(a, b);
    return __builtin_bit_cast(unsigned, r);
}
#else
static __device__ __forceinline__ unsigned pack2bf(float a, float b) {
    return (unsigned)f2bf(a) | ((unsigned)f2bf(b) << 16);
}
#endif
static __device__ __forceinline__ float hexp2(float x) {
    return __builtin_amdgcn_exp2f(x);
}
// async global->LDS, 16B per lane; LDS dest = wave-uniform base + lane*16
static __device__ __forceinline__ void gload16(const void* g, void* l) {
    __builtin_amdgcn_global_load_lds(
        (const __attribute__((address_space(1))) unsigned int*)g,
        (__attribute__((address_space(3))) unsigned int*)l, 16, 0, 0);
}

// Half-wave pair exchange: o0 = [x_lo, y_lo], o1 = [x_hi, y_hi].
#if __has_builtin(__builtin_amdgcn_permlane32_swap)
typedef __attribute__((ext_vector_type(2))) unsigned uint2v_t;
static __device__ __forceinline__ void plswap(unsigned x, unsigned y,
                                              unsigned& o0, unsigned& o1) {
    uint2v_t r = __builtin_amdgcn_permlane32_swap(x, y, false, false);
    o0 = r.x; o1 = r.y;
}
#else
static __device__ __forceinline__ void plswap(unsigned x, unsigned y,
                                              unsigned& o0, unsigned& o1) {
    int l = (int)(threadIdx.x & 63);
    bool hi = l >= 32;
    unsigned xsw = (unsigned)__shfl((int)x, l ^ 32);
    unsigned ysw = (unsigned)__shfl((int)y, l ^ 32);
    o0 = hi ? ysw : x;     // lo: own x; hi: partner's y
    o1 = hi ? y : xsw;     // lo: partner's x; hi: own y
}
#endif

// ---------------- fused prep kernel ----------------
__global__ __launch_bounds__(256) void prep(
    const float* __restrict__ x, ushort_t* __restrict__ xb,
    const float* __restrict__ Wqkv, ushort_t* __restrict__ wqT,
    const float* __restrict__ Wout, ushort_t* __restrict__ woT,
    const int* __restrict__ mask, float* __restrict__ maddg)
{
    __shared__ float tile[32][33];
    const int bk = blockIdx.x;
    const int t = threadIdx.x;
    if (bk < 4096) {
        int i = bk * 256 + t;
        float4 v = ((const float4*)x)[i];
        uint2 o;
        o.x = pack2bf(v.x, v.y);
        o.y = pack2bf(v.z, v.w);
        ((uint2*)xb)[i] = o;
        return;
    }
    if (bk < 8192) {
        const float* W; ushort_t* WT; int K, N, id;
        if (bk < 7168) { W = Wqkv; WT = wqT; K = 1024; N = 3072; id = bk - 4096;
                         int nb = (id % 96) * 32, kb = (id / 96) * 32;
                         const int r = t >> 3, c4 = (t & 7) * 4;
                         float4 v = *(const float4*)&W[(size_t)(kb + r) * N + nb + c4];
                         tile[r][c4+0]=v.x; tile[r][c4+1]=v.y; tile[r][c4+2]=v.z; tile[r][c4+3]=v.w;
                         __syncthreads();
                         uint2 o;
                         o.x = pack2bf(tile[c4+0][r], tile[c4+1][r]);
                         o.y = pack2bf(tile[c4+2][r], tile[c4+3][r]);
                         ((uint2*)WT)[((size_t)(nb + r) * K + kb + c4) >> 2] = o;
        } else {         W = Wout; WT = woT; K = 1024; N = 1024; id = bk - 7168;
                         int nb = (id % 32) * 32, kb = (id / 32) * 32;
                         const int r = t >> 3, c4 = (t & 7) * 4;
                         float4 v = *(const float4*)&W[(size_t)(kb + r) * N + nb + c4];
                         tile[r][c4+0]=v.x; tile[r][c4+1]=v.y; tile[r][c4+2]=v.z; tile[r][c4+3]=v.w;
                         __syncthreads();
                         uint2 o;
                         o.x = pack2bf(tile[c4+0][r], tile[c4+1][r]);
                         o.y = pack2bf(tile[c4+2][r], tile[c4+3][r]);
                         ((uint2*)WT)[((size_t)(nb + r) * K + kb + c4) >> 2] = o;
        }
        return;
    }
    {
        int i = (bk - 8192) * 256 + t;      // 4096 total
        maddg[i] = (mask[i] ? 0.f : -1e30f) - 24.0f;
    }
}

// ---------------- GEMM1: qkv projection ----------------
__global__ __launch_bounds__(256, 3) void gemm_qkv(
    const ushort_t* __restrict__ A, const ushort_t* __restrict__ B,
    const float* __restrict__ bias, ushort_t* __restrict__ qkvb,
    ushort_t* __restrict__ vtg)
{
    const int K = 1024;
    __shared__ ushort_t Ah[128][32], Bh[128][32];
    __shared__ ushort_t Tb[64][136];         // V-transpose bounce, 16B-aligned rows
    const int bn = blockIdx.x * 128, bm = blockIdx.y * 128;
    const int t = threadIdx.x, w = t >> 6, lane = t & 63;
    const int l15 = lane & 15, quad = lane >> 4;
    const int wm = w >> 1, wn = w & 1;

    const int srow = w * 32 + (lane >> 2);
    const int skp  = (lane & 3) ^ ((lane >> 2) & 3);     // swizzled global k-part
    const int scol = skp * 8;
    const ushort_t* ga = A + (size_t)(bm + srow) * K + scol;
    const ushort_t* gb = B + (size_t)(bn + srow) * K + scol;
    const size_t rstep = (size_t)16 * K;
    const int fcol = ((quad ^ (l15 & 3)) * 8);           // frag read col (deswizzle)

    floatx4 acc[4][4];
    #pragma unroll
    for (int mt = 0; mt < 4; ++mt)
        #pragma unroll
        for (int nt = 0; nt < 4; ++nt) acc[mt][nt] = (floatx4){0.f, 0.f, 0.f, 0.f};

    for (int k0 = 0; k0 < K; k0 += 32) {
        #pragma unroll
        for (int i = 0; i < 2; ++i) {
            gload16(ga + i * rstep + k0, &Ah[w * 32 + i * 16][0]);
            gload16(gb + i * rstep + k0, &Bh[w * 32 + i * 16][0]);
        }
        __syncthreads();
        short8 ah[4], bh[4];
        #pragma unroll
        for (int x = 0; x < 4; ++x) {
            ah[x] = *(const short8*)&Ah[wm * 64 + x * 16 + l15][fcol];
            bh[x] = *(const short8*)&Bh[wn * 64 + x * 16 + l15][fcol];
        }
        #pragma unroll
        for (int mt = 0; mt < 4; ++mt)
            #pragma unroll
            for (int nt = 0; nt < 4; ++nt)
                acc[mt][nt] = __builtin_amdgcn_mfma_f32_16x16x32_bf16(ah[mt], bh[nt], acc[mt][nt], 0, 0, 0);
        __syncthreads();
    }

    if (bn < 2048) {
        #pragma unroll
        for (int mt = 0; mt < 4; ++mt)
            #pragma unroll
            for (int r = 0; r < 4; ++r) {
                size_t row = (size_t)(bm + wm * 64 + mt * 16 + quad * 4 + r) * 2048;
                #pragma unroll
                for (int nt = 0; nt < 4; ++nt) {
                    int col = bn + wn * 64 + nt * 16 + l15;
                    qkvb[row + col] = f2bf(acc[mt][nt][r] + bias[col]);
                }
            }
    } else {
        // V block: LDS bounce -> vtg[b][h][d][s], one head (64 d) per pass
        const int h0 = (bn - 2048) >> 6;
        const int b  = bm >> 11, s0 = bm & 2047;
        #pragma unroll
        for (int hh = 0; hh < 2; ++hh) {
            if (wn == hh) {
                #pragma unroll
                for (int mt = 0; mt < 4; ++mt)
                    #pragma unroll
                    for (int nt = 0; nt < 4; ++nt) {
                        int d = nt * 16 + l15;
                        int sb = wm * 64 + mt * 16 + quad * 4;
                        float bv = bias[bn + hh * 64 + nt * 16 + l15];
                        uint2 pk;
                        pk.x = pack2bf(acc[mt][nt][0] + bv, acc[mt][nt][1] + bv);
                        pk.y = pack2bf(acc[mt][nt][2] + bv, acc[mt][nt][3] + bv);
                        *(uint2*)&Tb[d][sb] = pk;
                    }
            }
            __syncthreads();
            ushort_t* vbase = vtg + ((size_t)((b * 16 + h0 + hh) * 64)) * 2048 + s0;
            #pragma unroll
            for (int it = 0; it < 4; ++it) {
                int idx = t + it * 256;          // 0..1023
                int d = idx >> 4, ch = idx & 15;
                uint4 v = *(const uint4*)&Tb[d][ch * 8];
                *(uint4*)&vbase[(size_t)d * 2048 + ch * 8] = v;
            }
            __syncthreads();
        }
    }
}

// ---------------- GEMM3: 64x128 tile, fp32 output ----------------
__global__ __launch_bounds__(256, 3) void gemm_bf16_f32_64(
    const ushort_t* __restrict__ A, const ushort_t* __restrict__ B,
    const float* __restrict__ bias, float* __restrict__ C,
    int M, int N, int K)
{
    __shared__ ushort_t Ah[64][32], Bh[128][32];
    const int bn = blockIdx.x * 128, bm = blockIdx.y * 64;
    const int t = threadIdx.x, w = t >> 6, lane = t & 63;
    const int l15 = lane & 15, quad = lane >> 4;
    const int wm = w >> 1, wn = w & 1;          // wave-tile 32x64

    const int srow = w * 16 + (lane >> 2);
    const int skp  = (lane & 3) ^ ((lane >> 2) & 3);
    const int scol = skp * 8;
    const ushort_t* ga  = A + (size_t)(bm + srow) * K + scol;
    const ushort_t* gb0 = B + (size_t)(bn + srow) * K + scol;
    const ushort_t* gb1 = B + (size_t)(bn + 64 + srow) * K + scol;
    const int fcol = ((quad ^ (l15 & 3)) * 8);

    floatx4 acc[2][4];
    #pragma unroll
    for (int mt = 0; mt < 2; ++mt)
        #pragma unroll
        for (int nt = 0; nt < 4; ++nt) acc[mt][nt] = (floatx4){0.f, 0.f, 0.f, 0.f};

    for (int k0 = 0; k0 < K; k0 += 32) {
        gload16(ga  + k0, &Ah[w * 16][0]);
        gload16(gb0 + k0, &Bh[w * 16][0]);
        gload16(gb1 + k0, &Bh[64 + w * 16][0]);
        __syncthreads();
        short8 ah[2], bh[4];
        #pragma unroll
        for (int x = 0; x < 2; ++x)
            ah[x] = *(const short8*)&Ah[wm * 32 + x * 16 + l15][fcol];
        #pragma unroll
        for (int x = 0; x < 4; ++x)
            bh[x] = *(const short8*)&Bh[wn * 64 + x * 16 + l15][fcol];
        #pragma unroll
        for (int mt = 0; mt < 2; ++mt)
            #pragma unroll
            for (int nt = 0; nt < 4; ++nt)
                acc[mt][nt] = __builtin_amdgcn_mfma_f32_16x16x32_bf16(ah[mt], bh[nt], acc[mt][nt], 0, 0, 0);
        __syncthreads();
    }
    #pragma unroll
    for (int mt = 0; mt < 2; ++mt)
        #pragma unroll
        for (int r = 0; r < 4; ++r) {
            size_t row = (size_t)(bm + wm * 32 + mt * 16 + quad * 4 + r) * N;
            #pragma unroll
            for (int nt = 0; nt < 4; ++nt) {
                int col = bn + wn * 64 + nt * 16 + l15;
                C[row + col] = acc[mt][nt][r] + bias[col];
            }
        }
}

// ---------------- MFMA flash attention v11 ----------------
// v10 -> v11: intra-block K-split for occupancy WITHOUT raising per-pipe
// demand. 8 waves/block: waves 0-3 (half=0) process keys [0,1024), waves
// 4-7 (half=1) keys [1024,2048), same 128 q-rows, 16 kt each.
// 4096 waves total = 4 waves/SIMD (v10: 2) -> LDS/VALU/MFMA phases of
// co-resident waves overlap instead of serializing (v8 evidence: wall ==
// dominant pipe at 4/SIMD, == sum of pipes at 2/SIMD).
// No running max (fixed -24 bias) => partials combine additively:
// waves 4-7 dump outacc+lsum to LDS (aliasing dead K/V bufs), one barrier,
// waves 0-3 add + normalize + store.
__global__ __launch_bounds__(512, 4) void flash_v11(
    const ushort_t* __restrict__ qkv, const ushort_t* __restrict__ vtg,
    const float* __restrict__ maddg, ushort_t* __restrict__ attn)
{
    __shared__ __align__(16) ushort_t Ks[2][2][64][64];  // [half][buf][key][dchunk^..]
    __shared__ __align__(16) ushort_t Vt[2][2][64][64];  // [half][buf][d][keychunk^..]

    const int blk = blockIdx.x;              // 0..511
    const int xcd = blk & 7, rr = blk >> 3;
    const int qi = rr & 15, g = xcd + 8 * (rr >> 4);     // g in [0,32)
    const int b = g >> 4, h = g & 15, q0 = qi * 128;

    const int t = threadIdx.x, wave = t >> 6, lane = t & 63;
    const int half = wave >> 2, wsub = wave & 3;
    const int l31 = lane & 31, hi = lane >> 5, l7 = lane & 7;
    const size_t bS = (size_t)b * 2048;
    const float c1 = 0.125f * 1.44269504088896340736f;   // (1/sqrt(D))*log2(e)

    // Q fragments (B operand): qf[ks] = Q[q=l31][d = ks*16 + hi*8 .. +7]
    short8 qf[4];
    {
        int q = q0 + wsub * 32 + l31;
        const ushort_t* qp = qkv + (bS + q) * 2048 + h * 64 + hi * 8;
        #pragma unroll
        for (int ks = 0; ks < 4; ++ks)
            qf[ks] = *(const short8*)(qp + ks * 16);
    }

    // staging: within its half's 64-key tile, each wave stages rows wsub*16..+15
    const int srow  = wsub * 16 + (lane >> 3);                 // row (key or d)
    const int schnk = ((lane & 7) ^ ((lane >> 3) & 7)) * 8;    // swizzled chunk
    const ushort_t* gK = qkv + (bS + half * 1024 + srow) * 2048 + 1024 + h * 64 + schnk;
    const ushort_t* gV = vtg + ((size_t)(b * 16 + h) * 64 + srow) * 2048 + half * 1024 + schnk;
    const float* gM = maddg + b * 2048 + half * 1024;

    gload16(gK,            &Ks[half][0][wsub * 16][0]);
    gload16(gK + 8 * 2048, &Ks[half][0][wsub * 16 + 8][0]);
    gload16(gV,            &Vt[half][0][wsub * 16][0]);
    gload16(gV + 8 * 2048, &Vt[half][0][wsub * 16 + 8][0]);
    __syncthreads();

    floatx16 outacc[2] = {};
    float lsum = 0.f;

    int cur = 0;
    for (int kt = 0; kt < 16; ++kt) {
        const int k0 = kt * 64;
        if (kt + 1 < 16) {
            const int kn = (kt + 1) * 64;
            const int nb = cur ^ 1;
            gload16(gK + (size_t)kn * 2048,       &Ks[half][nb][wsub * 16][0]);
            gload16(gK + (size_t)(kn + 8) * 2048, &Ks[half][nb][wsub * 16 + 8][0]);
            gload16(gV + kn,                      &Vt[half][nb][wsub * 16][0]);
            gload16(gV + kn + 8 * 2048,           &Vt[half][nb][wsub * 16 + 8][0]);
        }
        // mask-add terms (L1-hot): m4[t32][gr][j] for key = t32*32+gr*8+hi*4+j
        float4 m4[2][4];
        #pragma unroll
        for (int t32 = 0; t32 < 2; ++t32)
            #pragma unroll
            for (int gr = 0; gr < 4; ++gr)
                m4[t32][gr] = *(const float4*)&gM[k0 + t32 * 32 + gr * 8 + hi * 4];

        // QK^T: sc[t32] covers keys t32*32..+31 for q=l31
        floatx16 sc[2] = {};
        __builtin_amdgcn_s_setprio(1);
        #pragma unroll
        for (int t32 = 0; t32 < 2; ++t32)
            #pragma unroll
            for (int ks = 0; ks < 4; ++ks) {
                const int ch = ((2 * ks + hi) ^ l7) * 8;
                short8 ka = *(const short8*)&Ks[half][cur][t32 * 32 + l31][ch];
                sc[t32] = __builtin_amdgcn_mfma_f32_32x32x16_bf16(ka, qf[ks], sc[t32], 0, 0, 0);
            }
        __builtin_amdgcn_s_setprio(0);

        // softmax + pack: W[t32][gr][w] = bf16x2 of keys gr*8+hi*4+{2w,2w+1}
        unsigned W[2][4][2];
        #pragma unroll
        for (int t32 = 0; t32 < 2; ++t32)
            #pragma unroll
            for (int gr = 0; gr < 4; ++gr) {
                float p0 = hexp2(fmaf(sc[t32][gr * 4 + 0], c1, m4[t32][gr].x));
                float p1 = hexp2(fmaf(sc[t32][gr * 4 + 1], c1, m4[t32][gr].y));
                float p2 = hexp2(fmaf(sc[t32][gr * 4 + 2], c1, m4[t32][gr].z));
                float p3 = hexp2(fmaf(sc[t32][gr * 4 + 3], c1, m4[t32][gr].w));
                lsum += (p0 + p1) + (p2 + p3);
                W[t32][gr][0] = pack2bf(p0, p1);
                W[t32][gr][1] = pack2bf(p2, p3);
            }

        // PV: lane needs keys (ae+hi)*8..+7 of tile t32 for q=l31.
        #pragma unroll
        for (int ks2 = 0; ks2 < 4; ++ks2) {
            const int t32 = ks2 >> 1;
            const int ae  = (ks2 & 1) * 2;
            uint4 u;
            plswap(W[t32][ae][0], W[t32][ae + 1][0], u.x, u.z);
            plswap(W[t32][ae][1], W[t32][ae + 1][1], u.y, u.w);
            short8 pb = __builtin_bit_cast(short8, u);
            const int ch = ((2 * ks2 + hi) ^ l7) * 8;
            __builtin_amdgcn_s_setprio(1);
            #pragma unroll
            for (int dt = 0; dt < 2; ++dt) {
                short8 va = *(const short8*)&Vt[half][cur][dt * 32 + l31][ch];
                outacc[dt] = __builtin_amdgcn_mfma_f32_32x32x16_bf16(va, pb, outacc[dt], 0, 0, 0);
            }
            __builtin_amdgcn_s_setprio(0);
        }
        __syncthreads();
        cur ^= 1;
    }

    // ---- k-split recombine (after final barrier; K/V LDS is dead) ----
    lsum += __shfl_xor(lsum, 32);            // lanes l, l^32 cover complementary keys

    float* Obuf = (float*)&Ks[0][0][0][0];   // 4*64*32 f32 = 32 KB, aliases Ks
    float* Lbuf = (float*)&Vt[0][0][0][0];   // 4*32  f32, aliases Vt

    if (half == 1) {
        #pragma unroll
        for (int dt = 0; dt < 2; ++dt)
            #pragma unroll
            for (int i = 0; i < 16; ++i)
                Obuf[(wsub * 64 + lane) * 32 + ((dt * 16 + i) ^ l31)] = outacc[dt][i];
        Lbuf[wsub * 32 + l31] = lsum;        // lanes l,l+32 write same value
    }
    __syncthreads();
    if (half == 0) {
        float inv = 1.f / (lsum + Lbuf[wsub * 32 + l31]);
        int q = q0 + wsub * 32 + l31;
        ushort_t* orow = attn + (bS + q) * 1024 + h * 64;
        #pragma unroll
        for (int dt = 0; dt < 2; ++dt) {
            float o[16];
            #pragma unroll
            for (int i = 0; i < 16; ++i)
                o[i] = outacc[dt][i] + Obuf[(wsub * 64 + lane) * 32 + ((dt * 16 + i) ^ l31)];
            #pragma unroll
            for (int gr = 0; gr < 4; ++gr) {
                uint2 pk;
                pk.x = pack2bf(o[gr * 4 + 0] * inv, o[gr * 4 + 1] * inv);
                pk.y = pack2bf(o[gr * 4 + 2] * inv, o[gr * 4 + 3] * inv);
                *(uint2*)&orow[dt * 32 + gr * 8 + hi * 4] = pk;
            }
        }
    }
}

extern "C" void kernel_launch(void* const* d_in, const int* in_sizes, int n_in,
                              void* d_out, int out_size, void* d_ws, size_t ws_size,
                              hipStream_t stream) {
    const float* x    = (const float*)d_in[0];   // (2,2048,1024)
    const int*   mask = (const int*)  d_in[1];   // (2,2048)
    const float* Wqkv = (const float*)d_in[2];   // (1024,3072)
    const float* bqkv = (const float*)d_in[3];   // (3072,)
    const float* Wout = (const float*)d_in[4];   // (1024,1024)
    const float* bout = (const float*)d_in[5];   // (1024,)
    float* out = (float*)d_out;                  // (2,2048,1024) fp32

    char* ws = (char*)d_ws;
    ushort_t* xb    = (ushort_t*)(ws);                   //  8 MB [0, 8388608)
    ushort_t* wqT   = (ushort_t*)(ws + 8388608);         //  6 MB [.., 14680064)
    ushort_t* qkvb  = (ushort_t*)(ws + 14680064);        // 16 MB [.., 31457280) Q,K only
    ushort_t* vtg   = (ushort_t*)(ws + 31457280);        //  8 MB [.., 39845888)
    ushort_t* attnb = (ushort_t*)(ws + 39845888);        //  8 MB [.., 48234496)
    ushort_t* woT   = (ushort_t*)(ws + 48234496);        //  2 MB [.., 50331648)
    float*    maddg = (float*)   (ws + 50331648);        // 16 KB

    const int M = 4096, E = 1024, N3 = 3072;

    prep<<<dim3(8208), dim3(256), 0, stream>>>(
        x, xb, Wqkv, wqT, Wout, woT, mask, maddg);

    gemm_qkv<<<dim3(N3 / 128, M / 128), dim3(256), 0, stream>>>(
        xb, wqT, bqkv, qkvb, vtg);

    flash_v11<<<dim3(512), dim3(512), 0, stream>>>(qkvb, vtg, maddg, attnb);

    gemm_bf16_f32_64<<<dim3(E / 128, M / 64), dim3(256), 0, stream>>>(
        attnb, woT, bout, out, M, E, E);
}

// Round 6
// 197.043 us; speedup vs baseline: 1.0786x; 1.0786x over previous
//
#include <hip/hip_runtime.h>

// B=2, S=2048, E=1024, H=16, D=64; rows = B*S = 4096; 3E = 3072.

typedef __attribute__((ext_vector_type(8))) short short8;     // 8 bf16 (A/B frag)
typedef __attribute__((ext_vector_type(4))) short short4b;    // 4 bf16
typedef __attribute__((ext_vector_type(4))) float floatx4;    // 16x16 C/D frag
typedef __attribute__((ext_vector_type(16))) float floatx16;  // 32x32 C/D frag
typedef unsigned short ushort_t;

static __device__ __forceinline__ ushort_t f2bf(float f) {
    unsigned u = __float_as_uint(f);
    u += 0x7fffu + ((u >> 16) & 1u);      // round-to-nearest-even
    return (ushort_t)(u >> 16);
}
static __device__ __forceinline__ float bf2f(ushort_t h) {
    return __uint_as_float(((unsigned)h) << 16);
}
#if __has_builtin(__builtin_amdgcn_cvt_pk_bf16_f32)
typedef __attribute__((ext_vector_type(2))) __bf16 bf16x2_t;
static __device__ __forceinline__ unsigned pack2bf(float a, float b) {
    bf16x2_t r = __builtin_amdgcn_cvt_pk_bf16_f32(a, b);
    return __builtin_bit_cast(unsigned, r);
}
#else
static __device__ __forceinline__ unsigned pack2bf(float a, float b) {
    return (unsigned)f2bf(a) | ((unsigned)f2bf(b) << 16);
}
#endif
static __device__ __forceinline__ float hexp2(float x) {
    return __builtin_amdgcn_exp2f(x);
}
// async global->LDS, 16B per lane; LDS dest = wave-uniform base + lane*16
static __device__ __forceinline__ void gload16(const void* g, void* l) {
    __builtin_amdgcn_global_load_lds(
        (const __attribute__((address_space(1))) unsigned int*)g,
        (__attribute__((address_space(3))) unsigned int*)l, 16, 0, 0);
}

// Half-wave pair exchange: o0 = [x_lo, y_lo], o1 = [x_hi, y_hi].
#if __has_builtin(__builtin_amdgcn_permlane32_swap)
typedef __attribute__((ext_vector_type(2))) unsigned uint2v_t;
static __device__ __forceinline__ void plswap(unsigned x, unsigned y,
                                              unsigned& o0, unsigned& o1) {
    uint2v_t r = __builtin_amdgcn_permlane32_swap(x, y, false, false);
    o0 = r.x; o1 = r.y;
}
#else
static __device__ __forceinline__ void plswap(unsigned x, unsigned y,
                                              unsigned& o0, unsigned& o1) {
    int l = (int)(threadIdx.x & 63);
    bool hi = l >= 32;
    unsigned xsw = (unsigned)__shfl((int)x, l ^ 32);
    unsigned ysw = (unsigned)__shfl((int)y, l ^ 32);
    o0 = hi ? ysw : x;     // lo: own x; hi: partner's y
    o1 = hi ? y : xsw;     // lo: partner's x; hi: own y
}
#endif

// ---------------- fused prep kernel ----------------
__global__ __launch_bounds__(256) void prep(
    const float* __restrict__ x, ushort_t* __restrict__ xb,
    const float* __restrict__ Wqkv, ushort_t* __restrict__ wqT,
    const float* __restrict__ Wout, ushort_t* __restrict__ woT,
    const int* __restrict__ mask, float* __restrict__ maddg)
{
    __shared__ float tile[32][33];
    const int bk = blockIdx.x;
    const int t = threadIdx.x;
    if (bk < 4096) {
        int i = bk * 256 + t;
        float4 v = ((const float4*)x)[i];
        uint2 o;
        o.x = pack2bf(v.x, v.y);
        o.y = pack2bf(v.z, v.w);
        ((uint2*)xb)[i] = o;
        return;
    }
    if (bk < 8192) {
        const float* W; ushort_t* WT; int K, N, id;
        if (bk < 7168) { W = Wqkv; WT = wqT; K = 1024; N = 3072; id = bk - 4096;
                         int nb = (id % 96) * 32, kb = (id / 96) * 32;
                         const int r = t >> 3, c4 = (t & 7) * 4;
                         float4 v = *(const float4*)&W[(size_t)(kb + r) * N + nb + c4];
                         tile[r][c4+0]=v.x; tile[r][c4+1]=v.y; tile[r][c4+2]=v.z; tile[r][c4+3]=v.w;
                         __syncthreads();
                         uint2 o;
                         o.x = pack2bf(tile[c4+0][r], tile[c4+1][r]);
                         o.y = pack2bf(tile[c4+2][r], tile[c4+3][r]);
                         ((uint2*)WT)[((size_t)(nb + r) * K + kb + c4) >> 2] = o;
        } else {         W = Wout; WT = woT; K = 1024; N = 1024; id = bk - 7168;
                         int nb = (id % 32) * 32, kb = (id / 32) * 32;
                         const int r = t >> 3, c4 = (t & 7) * 4;
                         float4 v = *(const float4*)&W[(size_t)(kb + r) * N + nb + c4];
                         tile[r][c4+0]=v.x; tile[r][c4+1]=v.y; tile[r][c4+2]=v.z; tile[r][c4+3]=v.w;
                         __syncthreads();
                         uint2 o;
                         o.x = pack2bf(tile[c4+0][r], tile[c4+1][r]);
                         o.y = pack2bf(tile[c4+2][r], tile[c4+3][r]);
                         ((uint2*)WT)[((size_t)(nb + r) * K + kb + c4) >> 2] = o;
        }
        return;
    }
    {
        int i = (bk - 8192) * 256 + t;      // 4096 total
        maddg[i] = (mask[i] ? 0.f : -1e30f) - 24.0f;
    }
}

// ---------------- GEMM1: qkv projection ----------------
__global__ __launch_bounds__(256, 3) void gemm_qkv(
    const ushort_t* __restrict__ A, const ushort_t* __restrict__ B,
    const float* __restrict__ bias, ushort_t* __restrict__ qkvb,
    ushort_t* __restrict__ vtg)
{
    const int K = 1024;
    __shared__ ushort_t Ah[128][32], Bh[128][32];
    __shared__ ushort_t Tb[64][136];         // V-transpose bounce, 16B-aligned rows
    const int bn = blockIdx.x * 128, bm = blockIdx.y * 128;
    const int t = threadIdx.x, w = t >> 6, lane = t & 63;
    const int l15 = lane & 15, quad = lane >> 4;
    const int wm = w >> 1, wn = w & 1;

    const int srow = w * 32 + (lane >> 2);
    const int skp  = (lane & 3) ^ ((lane >> 2) & 3);     // swizzled global k-part
    const int scol = skp * 8;
    const ushort_t* ga = A + (size_t)(bm + srow) * K + scol;
    const ushort_t* gb = B + (size_t)(bn + srow) * K + scol;
    const size_t rstep = (size_t)16 * K;
    const int fcol = ((quad ^ (l15 & 3)) * 8);           // frag read col (deswizzle)

    floatx4 acc[4][4];
    #pragma unroll
    for (int mt = 0; mt < 4; ++mt)
        #pragma unroll
        for (int nt = 0; nt < 4; ++nt) acc[mt][nt] = (floatx4){0.f, 0.f, 0.f, 0.f};

    for (int k0 = 0; k0 < K; k0 += 32) {
        #pragma unroll
        for (int i = 0; i < 2; ++i) {
            gload16(ga + i * rstep + k0, &Ah[w * 32 + i * 16][0]);
            gload16(gb + i * rstep + k0, &Bh[w * 32 + i * 16][0]);
        }
        __syncthreads();
        short8 ah[4], bh[4];
        #pragma unroll
        for (int x = 0; x < 4; ++x) {
            ah[x] = *(const short8*)&Ah[wm * 64 + x * 16 + l15][fcol];
            bh[x] = *(const short8*)&Bh[wn * 64 + x * 16 + l15][fcol];
        }
        #pragma unroll
        for (int mt = 0; mt < 4; ++mt)
            #pragma unroll
            for (int nt = 0; nt < 4; ++nt)
                acc[mt][nt] = __builtin_amdgcn_mfma_f32_16x16x32_bf16(ah[mt], bh[nt], acc[mt][nt], 0, 0, 0);
        __syncthreads();
    }

    if (bn < 2048) {
        #pragma unroll
        for (int mt = 0; mt < 4; ++mt)
            #pragma unroll
            for (int r = 0; r < 4; ++r) {
                size_t row = (size_t)(bm + wm * 64 + mt * 16 + quad * 4 + r) * 2048;
                #pragma unroll
                for (int nt = 0; nt < 4; ++nt) {
                    int col = bn + wn * 64 + nt * 16 + l15;
                    qkvb[row + col] = f2bf(acc[mt][nt][r] + bias[col]);
                }
            }
    } else {
        // V block: LDS bounce -> vtg[b][h][d][s], one head (64 d) per pass
        const int h0 = (bn - 2048) >> 6;
        const int b  = bm >> 11, s0 = bm & 2047;
        #pragma unroll
        for (int hh = 0; hh < 2; ++hh) {
            if (wn == hh) {
                #pragma unroll
                for (int mt = 0; mt < 4; ++mt)
                    #pragma unroll
                    for (int nt = 0; nt < 4; ++nt) {
                        int d = nt * 16 + l15;
                        int sb = wm * 64 + mt * 16 + quad * 4;
                        float bv = bias[bn + hh * 64 + nt * 16 + l15];
                        uint2 pk;
                        pk.x = pack2bf(acc[mt][nt][0] + bv, acc[mt][nt][1] + bv);
                        pk.y = pack2bf(acc[mt][nt][2] + bv, acc[mt][nt][3] + bv);
                        *(uint2*)&Tb[d][sb] = pk;
                    }
            }
            __syncthreads();
            ushort_t* vbase = vtg + ((size_t)((b * 16 + h0 + hh) * 64)) * 2048 + s0;
            #pragma unroll
            for (int it = 0; it < 4; ++it) {
                int idx = t + it * 256;          // 0..1023
                int d = idx >> 4, ch = idx & 15;
                uint4 v = *(const uint4*)&Tb[d][ch * 8];
                *(uint4*)&vbase[(size_t)d * 2048 + ch * 8] = v;
            }
            __syncthreads();
        }
    }
}

// ---------------- GEMM3: 64x128 tile, fp32 output ----------------
__global__ __launch_bounds__(256, 3) void gemm_bf16_f32_64(
    const ushort_t* __restrict__ A, const ushort_t* __restrict__ B,
    const float* __restrict__ bias, float* __restrict__ C,
    int M, int N, int K)
{
    __shared__ ushort_t Ah[64][32], Bh[128][32];
    const int bn = blockIdx.x * 128, bm = blockIdx.y * 64;
    const int t = threadIdx.x, w = t >> 6, lane = t & 63;
    const int l15 = lane & 15, quad = lane >> 4;
    const int wm = w >> 1, wn = w & 1;          // wave-tile 32x64

    const int srow = w * 16 + (lane >> 2);
    const int skp  = (lane & 3) ^ ((lane >> 2) & 3);
    const int scol = skp * 8;
    const ushort_t* ga  = A + (size_t)(bm + srow) * K + scol;
    const ushort_t* gb0 = B + (size_t)(bn + srow) * K + scol;
    const ushort_t* gb1 = B + (size_t)(bn + 64 + srow) * K + scol;
    const int fcol = ((quad ^ (l15 & 3)) * 8);

    floatx4 acc[2][4];
    #pragma unroll
    for (int mt = 0; mt < 2; ++mt)
        #pragma unroll
        for (int nt = 0; nt < 4; ++nt) acc[mt][nt] = (floatx4){0.f, 0.f, 0.f, 0.f};

    for (int k0 = 0; k0 < K; k0 += 32) {
        gload16(ga  + k0, &Ah[w * 16][0]);
        gload16(gb0 + k0, &Bh[w * 16][0]);
        gload16(gb1 + k0, &Bh[64 + w * 16][0]);
        __syncthreads();
        short8 ah[2], bh[4];
        #pragma unroll
        for (int x = 0; x < 2; ++x)
            ah[x] = *(const short8*)&Ah[wm * 32 + x * 16 + l15][fcol];
        #pragma unroll
        for (int x = 0; x < 4; ++x)
            bh[x] = *(const short8*)&Bh[wn * 64 + x * 16 + l15][fcol];
        #pragma unroll
        for (int mt = 0; mt < 2; ++mt)
            #pragma unroll
            for (int nt = 0; nt < 4; ++nt)
                acc[mt][nt] = __builtin_amdgcn_mfma_f32_16x16x32_bf16(ah[mt], bh[nt], acc[mt][nt], 0, 0, 0);
        __syncthreads();
    }
    #pragma unroll
    for (int mt = 0; mt < 2; ++mt)
        #pragma unroll
        for (int r = 0; r < 4; ++r) {
            size_t row = (size_t)(bm + wm * 32 + mt * 16 + quad * 4 + r) * N;
            #pragma unroll
            for (int nt = 0; nt < 4; ++nt) {
                int col = bn + wn * 64 + nt * 16 + l15;
                C[row + col] = acc[mt][nt][r] + bias[col];
            }
        }
}

// ---------------- MFMA flash attention v12 ----------------
// v11 -> v12: fix the spill. v11's counters showed VGPR_Count=64 with a
// ~100-reg live set -> scratch traffic (FETCH 12->33MB, WRITE 8->38MB).
// (a) amdgpu_waves_per_eu(4,4) pins the budget at 128 VGPR (LDS caps at
//     2 blocks/CU = 4 waves/SIMD anyway, so max=4 loses nothing);
// (b) per-t32 QK^T->softmax->pack so only one sc (16 regs) is live at a
//     time; m4 consumed immediately. Peak ~95 regs < 128.
// Structure (k-split across wave halves, additive recombine) unchanged.
__global__ __launch_bounds__(512)
__attribute__((amdgpu_waves_per_eu(4, 4)))
void flash_v12(
    const ushort_t* __restrict__ qkv, const ushort_t* __restrict__ vtg,
    const float* __restrict__ maddg, ushort_t* __restrict__ attn)
{
    __shared__ __align__(16) ushort_t Ks[2][2][64][64];  // [half][buf][key][dchunk^..]
    __shared__ __align__(16) ushort_t Vt[2][2][64][64];  // [half][buf][d][keychunk^..]

    const int blk = blockIdx.x;              // 0..511
    const int xcd = blk & 7, rr = blk >> 3;
    const int qi = rr & 15, g = xcd + 8 * (rr >> 4);     // g in [0,32)
    const int b = g >> 4, h = g & 15, q0 = qi * 128;

    const int t = threadIdx.x, wave = t >> 6, lane = t & 63;
    const int half = wave >> 2, wsub = wave & 3;
    const int l31 = lane & 31, hi = lane >> 5, l7 = lane & 7;
    const size_t bS = (size_t)b * 2048;
    const float c1 = 0.125f * 1.44269504088896340736f;   // (1/sqrt(D))*log2(e)

    // Q fragments (B operand): qf[ks] = Q[q=l31][d = ks*16 + hi*8 .. +7]
    short8 qf[4];
    {
        int q = q0 + wsub * 32 + l31;
        const ushort_t* qp = qkv + (bS + q) * 2048 + h * 64 + hi * 8;
        #pragma unroll
        for (int ks = 0; ks < 4; ++ks)
            qf[ks] = *(const short8*)(qp + ks * 16);
    }

    // staging: within its half's 64-key tile, each wave stages rows wsub*16..+15
    const int srow  = wsub * 16 + (lane >> 3);                 // row (key or d)
    const int schnk = ((lane & 7) ^ ((lane >> 3) & 7)) * 8;    // swizzled chunk
    const ushort_t* gK = qkv + (bS + half * 1024 + srow) * 2048 + 1024 + h * 64 + schnk;
    const ushort_t* gV = vtg + ((size_t)(b * 16 + h) * 64 + srow) * 2048 + half * 1024 + schnk;
    const float* gM = maddg + b * 2048 + half * 1024;

    gload16(gK,            &Ks[half][0][wsub * 16][0]);
    gload16(gK + 8 * 2048, &Ks[half][0][wsub * 16 + 8][0]);
    gload16(gV,            &Vt[half][0][wsub * 16][0]);
    gload16(gV + 8 * 2048, &Vt[half][0][wsub * 16 + 8][0]);
    __syncthreads();

    floatx16 outacc[2] = {};
    float lsum = 0.f;

    int cur = 0;
    for (int kt = 0; kt < 16; ++kt) {
        const int k0 = kt * 64;
        if (kt + 1 < 16) {
            const int kn = (kt + 1) * 64;
            const int nb = cur ^ 1;
            gload16(gK + (size_t)kn * 2048,       &Ks[half][nb][wsub * 16][0]);
            gload16(gK + (size_t)(kn + 8) * 2048, &Ks[half][nb][wsub * 16 + 8][0]);
            gload16(gV + kn,                      &Vt[half][nb][wsub * 16][0]);
            gload16(gV + kn + 8 * 2048,           &Vt[half][nb][wsub * 16 + 8][0]);
        }

        // per-t32: QK^T then softmax+pack (only one sc live at a time)
        unsigned W[2][4][2];
        #pragma unroll
        for (int t32 = 0; t32 < 2; ++t32) {
            floatx16 sc = {};
            __builtin_amdgcn_s_setprio(1);
            #pragma unroll
            for (int ks = 0; ks < 4; ++ks) {
                const int ch = ((2 * ks + hi) ^ l7) * 8;
                short8 ka = *(const short8*)&Ks[half][cur][t32 * 32 + l31][ch];
                sc = __builtin_amdgcn_mfma_f32_32x32x16_bf16(ka, qf[ks], sc, 0, 0, 0);
            }
            __builtin_amdgcn_s_setprio(0);
            #pragma unroll
            for (int gr = 0; gr < 4; ++gr) {
                float4 m4 = *(const float4*)&gM[k0 + t32 * 32 + gr * 8 + hi * 4];
                float p0 = hexp2(fmaf(sc[gr * 4 + 0], c1, m4.x));
                float p1 = hexp2(fmaf(sc[gr * 4 + 1], c1, m4.y));
                float p2 = hexp2(fmaf(sc[gr * 4 + 2], c1, m4.z));
                float p3 = hexp2(fmaf(sc[gr * 4 + 3], c1, m4.w));
                lsum += (p0 + p1) + (p2 + p3);
                W[t32][gr][0] = pack2bf(p0, p1);
                W[t32][gr][1] = pack2bf(p2, p3);
            }
        }

        // PV: lane needs keys (ae+hi)*8..+7 of tile t32 for q=l31.
        #pragma unroll
        for (int ks2 = 0; ks2 < 4; ++ks2) {
            const int t32 = ks2 >> 1;
            const int ae  = (ks2 & 1) * 2;
            uint4 u;
            plswap(W[t32][ae][0], W[t32][ae + 1][0], u.x, u.z);
            plswap(W[t32][ae][1], W[t32][ae + 1][1], u.y, u.w);
            short8 pb = __builtin_bit_cast(short8, u);
            const int ch = ((2 * ks2 + hi) ^ l7) * 8;
            __builtin_amdgcn_s_setprio(1);
            #pragma unroll
            for (int dt = 0; dt < 2; ++dt) {
                short8 va = *(const short8*)&Vt[half][cur][dt * 32 + l31][ch];
                outacc[dt] = __builtin_amdgcn_mfma_f32_32x32x16_bf16(va, pb, outacc[dt], 0, 0, 0);
            }
            __builtin_amdgcn_s_setprio(0);
        }
        __syncthreads();
        cur ^= 1;
    }

    // ---- k-split recombine (after final barrier; K/V LDS is dead) ----
    lsum += __shfl_xor(lsum, 32);            // lanes l, l^32 cover complementary keys

    float* Obuf = (float*)&Ks[0][0][0][0];   // 4*64*32 f32 = 32 KB, aliases Ks
    float* Lbuf = (float*)&Vt[0][0][0][0];   // 4*32  f32, aliases Vt

    if (half == 1) {
        #pragma unroll
        for (int dt = 0; dt < 2; ++dt)
            #pragma unroll
            for (int i = 0; i < 16; ++i)
                Obuf[(wsub * 64 + lane) * 32 + ((dt * 16 + i) ^ l31)] = outacc[dt][i];
        Lbuf[wsub * 32 + l31] = lsum;        // lanes l,l+32 write same value
    }
    __syncthreads();
    if (half == 0) {
        float inv = 1.f / (lsum + Lbuf[wsub * 32 + l31]);
        int q = q0 + wsub * 32 + l31;
        ushort_t* orow = attn + (bS + q) * 1024 + h * 64;
        #pragma unroll
        for (int dt = 0; dt < 2; ++dt) {
            float o[16];
            #pragma unroll
            for (int i = 0; i < 16; ++i)
                o[i] = outacc[dt][i] + Obuf[(wsub * 64 + lane) * 32 + ((dt * 16 + i) ^ l31)];
            #pragma unroll
            for (int gr = 0; gr < 4; ++gr) {
                uint2 pk;
                pk.x = pack2bf(o[gr * 4 + 0] * inv, o[gr * 4 + 1] * inv);
                pk.y = pack2bf(o[gr * 4 + 2] * inv, o[gr * 4 + 3] * inv);
                *(uint2*)&orow[dt * 32 + gr * 8 + hi * 4] = pk;
            }
        }
    }
}

extern "C" void kernel_launch(void* const* d_in, const int* in_sizes, int n_in,
                              void* d_out, int out_size, void* d_ws, size_t ws_size,
                              hipStream_t stream) {
    const float* x    = (const float*)d_in[0];   // (2,2048,1024)
    const int*   mask = (const int*)  d_in[1];   // (2,2048)
    const float* Wqkv = (const float*)d_in[2];   // (1024,3072)
    const float* bqkv = (const float*)d_in[3];   // (3072,)
    const float* Wout = (const float*)d_in[4];   // (1024,1024)
    const float* bout = (const float*)d_in[5];   // (1024,)
    float* out = (float*)d_out;                  // (2,2048,1024) fp32

    char* ws = (char*)d_ws;
    ushort_t* xb    = (ushort_t*)(ws);                   //  8 MB [0, 8388608)
    ushort_t* wqT   = (ushort_t*)(ws + 8388608);         //  6 MB [.., 14680064)
    ushort_t* qkvb  = (ushort_t*)(ws + 14680064);        // 16 MB [.., 31457280) Q,K only
    ushort_t* vtg   = (ushort_t*)(ws + 31457280);        //  8 MB [.., 39845888)
    ushort_t* attnb = (ushort_t*)(ws + 39845888);        //  8 MB [.., 48234496)
    ushort_t* woT   = (ushort_t*)(ws + 48234496);        //  2 MB [.., 50331648)
    float*    maddg = (float*)   (ws + 50331648);        // 16 KB

    const int M = 4096, E = 1024, N3 = 3072;

    prep<<<dim3(8208), dim3(256), 0, stream>>>(
        x, xb, Wqkv, wqT, Wout, woT, mask, maddg);

    gemm_qkv<<<dim3(N3 / 128, M / 128), dim3(256), 0, stream>>>(
        xb, wqT, bqkv, qkvb, vtg);

    flash_v12<<<dim3(512), dim3(512), 0, stream>>>(qkvb, vtg, maddg, attnb);

    gemm_bf16_f32_64<<<dim3(E / 128, M / 64), dim3(256), 0, stream>>>(
        attnb, woT, bout, out, M, E, E);
}